// Round 6
// baseline (1320.097 us; speedup 1.0000x reference)
//
#include <hip/hip_runtime.h>

constexpr int NFEAT = 256;
constexpr int NHID  = 128;
constexpr int SCAN_B = 4096;   // elements per scan block (1024 threads x 4)

// ---------------- CSR build ----------------

__global__ void hist_kernel(const int* __restrict__ rows, int* __restrict__ cnt, int n) {
  int i = blockIdx.x * blockDim.x + threadIdx.x;
  if (i < n) atomicAdd(&cnt[rows[i]], 1);
}

__global__ void scan1_kernel(const int* __restrict__ cnt, int* __restrict__ part,
                             int* __restrict__ bsum, int n) {
  __shared__ int tmp[1024];
  int tid = threadIdx.x;
  int base = blockIdx.x * SCAN_B + tid * 4;
  int4 v = make_int4(0, 0, 0, 0);
  if (base + 4 <= n) {
    v = *(const int4*)&cnt[base];
  } else {
    if (base + 0 < n) v.x = cnt[base + 0];
    if (base + 1 < n) v.y = cnt[base + 1];
    if (base + 2 < n) v.z = cnt[base + 2];
    if (base + 3 < n) v.w = cnt[base + 3];
  }
  int s = v.x + v.y + v.z + v.w;
  tmp[tid] = s;
  __syncthreads();
  for (int off = 1; off < 1024; off <<= 1) {
    int t = (tid >= off) ? tmp[tid - off] : 0;
    __syncthreads();
    tmp[tid] += t;
    __syncthreads();
  }
  int excl = tmp[tid] - s;
  if (base + 0 < n) part[base + 0] = excl;
  if (base + 1 < n) part[base + 1] = excl + v.x;
  if (base + 2 < n) part[base + 2] = excl + v.x + v.y;
  if (base + 3 < n) part[base + 3] = excl + v.x + v.y + v.z;
  if (tid == 1023) bsum[blockIdx.x] = tmp[1023];
}

__global__ void scan2_kernel(int* __restrict__ bsum, int nb) {
  if (threadIdx.x == 0 && blockIdx.x == 0) {
    int run = 0;
    for (int i = 0; i < nb; ++i) { int t = bsum[i]; bsum[i] = run; run += t; }
    bsum[nb] = run;
  }
}

__global__ void scan3_kernel(int* __restrict__ row_ptr, const int* __restrict__ bsum,
                             int* __restrict__ cursor, int n, int nb) {
  int i = blockIdx.x * blockDim.x + threadIdx.x;
  if (i < n) {
    int v = row_ptr[i] + bsum[i / SCAN_B];
    row_ptr[i] = v;
    cursor[i]  = v;
  }
  if (i == 0) row_ptr[n] = bsum[nb];
}

// scatter only a 4B permutation index: halves random-write line traffic.
// spmm re-gathers (col,val) through perm from the original edge arrays.
__global__ void scatter_kernel(const int* __restrict__ rows, int* __restrict__ cursor,
                               int* __restrict__ perm, int n) {
  int i = blockIdx.x * blockDim.x + threadIdx.x;
  if (i < n) {
    int p = atomicAdd(&cursor[rows[i]], 1);
    perm[p] = i;
  }
}

// ---------------- dense GEMM: C[M,128] = A[M,K] @ W[K,128] ----------------
// m97-style 2-phase pipeline: BM=128, BN=128, BK=16, 256 threads, 8x8/thread.
// Double-buffered LDS staged entirely by global_load_lds (width 16) -> zero
// staging VGPRs. A row-major in LDS; 4-way read conflict fixed by
// pre-swizzling the per-lane GLOBAL source (q ^= (row>>2)&3 on f4-quads) and
// applying the same XOR on the LDS read (linear gload_lds dest, m173).
// No min-waves clamp: grid is ~3 blocks/CU anyway, let VGPRs float (~120 live)

__device__ __forceinline__ void gload16(const float* src, float* dst_lds) {
  __builtin_amdgcn_global_load_lds(
      (const __attribute__((address_space(1))) void*)src,
      (__attribute__((address_space(3))) void*)dst_lds,
      16, 0, 0);
}

template<int K>
__global__ __launch_bounds__(256) void gemm_kernel(const float* __restrict__ A,
                                                   const float* __restrict__ W,
                                                   float* __restrict__ C, int M) {
  // float4-slot layouts: As slot = row*4 + (q ^ ((row>>2)&3)), q = k-quad 0..3
  //                      Bs slot = k*32 + colquad
  __shared__ __align__(16) float As[2][2048];   // 8 KB per buffer
  __shared__ __align__(16) float Bs[2][2048];   // 8 KB per buffer
  const int tid  = threadIdx.x;
  const int w    = tid >> 6;
  const int lane = tid & 63;
  const int r8   = tid >> 4;   // 0..15 -> rows r8*4+i (+64)
  const int c8   = tid & 15;   // 0..15 -> cols c8*4 (+64)
  const int block_row = blockIdx.x * 128;

  float acc[2][2][4][4] = {};   // [rh][ch][i][j]

  auto prefetch = [&](int t) {
    const int buf = t & 1;
    const int k0  = t * 16;
    #pragma unroll
    for (int j = 0; j < 2; ++j) {
      int s   = j * 256 + w * 64 + lane;      // A f4-slot this lane fills
      int row = s >> 2;
      int q   = (s & 3) ^ ((row >> 2) & 3);   // source pre-swizzle
      int grow = block_row + row;
      if (grow >= M) grow = M - 1;            // clamp: garbage lands in dead rows
      gload16(A + (size_t)grow * K + k0 + q * 4,
              &As[buf][(j * 256 + w * 64) * 4]);
    }
    #pragma unroll
    for (int j = 0; j < 2; ++j) {
      int s = j * 256 + w * 64 + lane;        // B f4-slot
      int r = s >> 5, cq = s & 31;
      gload16(W + (size_t)(k0 + r) * 128 + cq * 4,
              &Bs[buf][(j * 256 + w * 64) * 4]);
    }
  };

  constexpr int NT = K / 16;
  prefetch(0);
  for (int t = 0; t < NT; ++t) {
    __syncthreads();                 // drains tile-t loads (compiler vmcnt(0))
    if (t + 1 < NT) prefetch(t + 1); // in flight across compute(t)
    const float* as = As[t & 1];
    const float* bs = Bs[t & 1];
    #pragma unroll
    for (int q = 0; q < 4; ++q) {    // 4 k-quads = 16 kk
      // hold the A block (8 float4 = 32 regs), stream B in pairs (8 regs)
      float av[2][4][4];
      #pragma unroll
      for (int rh = 0; rh < 2; ++rh)
        #pragma unroll
        for (int i = 0; i < 4; ++i) {
          int row = rh * 64 + r8 * 4 + i;
          float4 a = *(const float4*)&as[(row * 4 + (q ^ ((row >> 2) & 3))) * 4];
          av[rh][i][0] = a.x; av[rh][i][1] = a.y;
          av[rh][i][2] = a.z; av[rh][i][3] = a.w;
        }
      #pragma unroll
      for (int j = 0; j < 4; ++j) {
        int kk = q * 4 + j;
        float4 b0 = *(const float4*)&bs[(kk * 32 + c8) * 4];
        float4 b1 = *(const float4*)&bs[(kk * 32 + 16 + c8) * 4];
        #pragma unroll
        for (int rh = 0; rh < 2; ++rh)
          #pragma unroll
          for (int i = 0; i < 4; ++i) {
            float a = av[rh][i][j];
            acc[rh][0][i][0] += a * b0.x; acc[rh][0][i][1] += a * b0.y;
            acc[rh][0][i][2] += a * b0.z; acc[rh][0][i][3] += a * b0.w;
            acc[rh][1][i][0] += a * b1.x; acc[rh][1][i][1] += a * b1.y;
            acc[rh][1][i][2] += a * b1.z; acc[rh][1][i][3] += a * b1.w;
          }
      }
    }
  }

  #pragma unroll
  for (int rh = 0; rh < 2; ++rh)
    #pragma unroll
    for (int i = 0; i < 4; ++i) {
      int grow = block_row + rh * 64 + r8 * 4 + i;
      if (grow < M) {
        #pragma unroll
        for (int ch = 0; ch < 2; ++ch) {
          float4 v = make_float4(acc[rh][ch][i][0], acc[rh][ch][i][1],
                                 acc[rh][ch][i][2], acc[rh][ch][i][3]);
          *(float4*)&C[(size_t)grow * 128 + ch * 64 + c8 * 4] = v;
        }
      }
    }
}

// ---------------- SpMM + bias + ReLU ----------------
// one 64-lane wave per output row; lane preloads one edge via perm
// indirection (perm coalesced, col/val 4B gathers from warm L2/L3);
// per-edge values via __shfl broadcast; unroll x8, dual acc chains.

__global__ void spmm_kernel(const float* __restrict__ support, const int* __restrict__ row_ptr,
                            const int* __restrict__ perm, const int* __restrict__ ecol,
                            const float* __restrict__ evl, const float* __restrict__ bias,
                            float* __restrict__ out, int n_nodes) {
  int row  = blockIdx.x * (blockDim.x >> 6) + (threadIdx.x >> 6);
  int lane = threadIdx.x & 63;
  if (row >= n_nodes) return;
  int beg = row_ptr[row], end = row_ptr[row + 1];
  float ax0 = 0.f, ay0 = 0.f, ax1 = 0.f, ay1 = 0.f;
  for (int chunk = beg; chunk < end; chunk += 64) {
    int idx = chunk + lane;
    int m = min(64, end - chunk);
    int ie = (idx < end) ? perm[idx] : 0;
    int   cl = ecol[ie];
    float vl = (idx < end) ? evl[ie] : 0.f;
    int e = 0;
    for (; e + 8 <= m; e += 8) {
      int   c0 = __shfl(cl, e + 0), c1 = __shfl(cl, e + 1);
      int   c2 = __shfl(cl, e + 2), c3 = __shfl(cl, e + 3);
      int   c4 = __shfl(cl, e + 4), c5 = __shfl(cl, e + 5);
      int   c6 = __shfl(cl, e + 6), c7 = __shfl(cl, e + 7);
      float v0 = __shfl(vl, e + 0), v1 = __shfl(vl, e + 1);
      float v2 = __shfl(vl, e + 2), v3 = __shfl(vl, e + 3);
      float v4 = __shfl(vl, e + 4), v5 = __shfl(vl, e + 5);
      float v6 = __shfl(vl, e + 6), v7 = __shfl(vl, e + 7);
      float2 s0 = *(const float2*)&support[(size_t)c0 * 128 + lane * 2];
      float2 s1 = *(const float2*)&support[(size_t)c1 * 128 + lane * 2];
      float2 s2 = *(const float2*)&support[(size_t)c2 * 128 + lane * 2];
      float2 s3 = *(const float2*)&support[(size_t)c3 * 128 + lane * 2];
      float2 s4 = *(const float2*)&support[(size_t)c4 * 128 + lane * 2];
      float2 s5 = *(const float2*)&support[(size_t)c5 * 128 + lane * 2];
      float2 s6 = *(const float2*)&support[(size_t)c6 * 128 + lane * 2];
      float2 s7 = *(const float2*)&support[(size_t)c7 * 128 + lane * 2];
      ax0 += v0 * s0.x; ay0 += v0 * s0.y;
      ax1 += v1 * s1.x; ay1 += v1 * s1.y;
      ax0 += v2 * s2.x; ay0 += v2 * s2.y;
      ax1 += v3 * s3.x; ay1 += v3 * s3.y;
      ax0 += v4 * s4.x; ay0 += v4 * s4.y;
      ax1 += v5 * s5.x; ay1 += v5 * s5.y;
      ax0 += v6 * s6.x; ay0 += v6 * s6.y;
      ax1 += v7 * s7.x; ay1 += v7 * s7.y;
    }
    for (; e < m; ++e) {
      int   ce = __shfl(cl, e);
      float ve = __shfl(vl, e);
      float2 s = *(const float2*)&support[(size_t)ce * 128 + lane * 2];
      ax0 += ve * s.x; ay0 += ve * s.y;
    }
  }
  float accx = ax0 + ax1, accy = ay0 + ay1;
  float2 b = *(const float2*)&bias[lane * 2];
  float2 o = make_float2(fmaxf(accx + b.x, 0.f), fmaxf(accy + b.y, 0.f));
  *(float2*)&out[(size_t)row * 128 + lane * 2] = o;
}

// ---------------- launch ----------------

extern "C" void kernel_launch(void* const* d_in, const int* in_sizes, int n_in,
                              void* d_out, int out_size, void* d_ws, size_t ws_size,
                              hipStream_t stream) {
  const float* x    = (const float*)d_in[0];
  const int*   erow = (const int*)d_in[1];
  const int*   ecol = (const int*)d_in[2];
  const float* evl  = (const float*)d_in[3];
  const float* W1   = (const float*)d_in[4];
  const float* b1   = (const float*)d_in[5];
  const float* W2   = (const float*)d_in[6];
  const float* b2   = (const float*)d_in[7];
  int n_nodes = in_sizes[0] / NFEAT;
  int n_edges = in_sizes[1];
  float* out = (float*)d_out;

  char* ws = (char*)d_ws;
  size_t off = 0;
  auto alloc = [&](size_t bytes) -> void* {
    void* p = ws + off;
    off += bytes;
    off = (off + 255) & ~(size_t)255;
    return p;
  };
  float* support = (float*)alloc((size_t)n_nodes * NHID * sizeof(float));
  int*   cnt     = (int*)alloc((size_t)n_nodes * sizeof(int));
  int*   row_ptr = (int*)alloc(((size_t)n_nodes + 1) * sizeof(int));
  int*   cursor  = (int*)alloc((size_t)n_nodes * sizeof(int));
  int*   perm    = (int*)alloc((size_t)n_edges * sizeof(int));
  int nb = (n_nodes + SCAN_B - 1) / SCAN_B;
  int*   bsum    = (int*)alloc((size_t)(nb + 1) * sizeof(int));

  // CSR build (shared by all 5 layers)
  hipMemsetAsync(cnt, 0, (size_t)n_nodes * sizeof(int), stream);
  hist_kernel<<<(n_edges + 255) / 256, 256, 0, stream>>>(erow, cnt, n_edges);
  scan1_kernel<<<nb, 1024, 0, stream>>>(cnt, row_ptr, bsum, n_nodes);
  scan2_kernel<<<1, 64, 0, stream>>>(bsum, nb);
  scan3_kernel<<<(n_nodes + 255) / 256, 256, 0, stream>>>(row_ptr, bsum, cursor, n_nodes, nb);
  scatter_kernel<<<(n_edges + 255) / 256, 256, 0, stream>>>(erow, cursor, perm, n_edges);

  int gblocks = (n_nodes + 127) / 128;
  int sblocks = (n_nodes + 3) / 4;

  gemm_kernel<NFEAT><<<gblocks, 256, 0, stream>>>(x, W1, support, n_nodes);
  spmm_kernel<<<sblocks, 256, 0, stream>>>(support, row_ptr, perm, ecol, evl, b1, out, n_nodes);

  for (int l = 0; l < 4; ++l) {
    gemm_kernel<NHID><<<gblocks, 256, 0, stream>>>(out, W2, support, n_nodes);
    spmm_kernel<<<sblocks, 256, 0, stream>>>(support, row_ptr, perm, ecol, evl, b2, out, n_nodes);
  }
}

// Round 7
// 1053.662 us; speedup vs baseline: 1.2529x; 1.2529x over previous
//
#include <hip/hip_runtime.h>

constexpr int NFEAT = 256;
constexpr int NHID  = 128;
constexpr int SCAN_B = 4096;   // elements per scan block (1024 threads x 4)

// ---------------- CSR build ----------------

__global__ void hist_kernel(const int* __restrict__ rows, int* __restrict__ cnt, int n) {
  int i = blockIdx.x * blockDim.x + threadIdx.x;
  if (i < n) atomicAdd(&cnt[rows[i]], 1);
}

__global__ void scan1_kernel(const int* __restrict__ cnt, int* __restrict__ part,
                             int* __restrict__ bsum, int n) {
  __shared__ int tmp[1024];
  int tid = threadIdx.x;
  int base = blockIdx.x * SCAN_B + tid * 4;
  int4 v = make_int4(0, 0, 0, 0);
  if (base + 4 <= n) {
    v = *(const int4*)&cnt[base];
  } else {
    if (base + 0 < n) v.x = cnt[base + 0];
    if (base + 1 < n) v.y = cnt[base + 1];
    if (base + 2 < n) v.z = cnt[base + 2];
    if (base + 3 < n) v.w = cnt[base + 3];
  }
  int s = v.x + v.y + v.z + v.w;
  tmp[tid] = s;
  __syncthreads();
  for (int off = 1; off < 1024; off <<= 1) {
    int t = (tid >= off) ? tmp[tid - off] : 0;
    __syncthreads();
    tmp[tid] += t;
    __syncthreads();
  }
  int excl = tmp[tid] - s;
  if (base + 0 < n) part[base + 0] = excl;
  if (base + 1 < n) part[base + 1] = excl + v.x;
  if (base + 2 < n) part[base + 2] = excl + v.x + v.y;
  if (base + 3 < n) part[base + 3] = excl + v.x + v.y + v.z;
  if (tid == 1023) bsum[blockIdx.x] = tmp[1023];
}

__global__ void scan2_kernel(int* __restrict__ bsum, int nb) {
  if (threadIdx.x == 0 && blockIdx.x == 0) {
    int run = 0;
    for (int i = 0; i < nb; ++i) { int t = bsum[i]; bsum[i] = run; run += t; }
    bsum[nb] = run;
  }
}

__global__ void scan3_kernel(int* __restrict__ row_ptr, const int* __restrict__ bsum,
                             int* __restrict__ cursor, int n, int nb) {
  int i = blockIdx.x * blockDim.x + threadIdx.x;
  if (i < n) {
    int v = row_ptr[i] + bsum[i / SCAN_B];
    row_ptr[i] = v;
    cursor[i]  = v;
  }
  if (i == 0) row_ptr[n] = bsum[nb];
}

// pack (col, val) into one 8B store (round-5 best config; perm indirection
// measured -275us worse: random 4B re-gathers fetch a full line each)
__global__ void scatter_kernel(const int* __restrict__ rows, const int* __restrict__ cols,
                               const float* __restrict__ vals, int* __restrict__ cursor,
                               int2* __restrict__ ev_s, int n) {
  int i = blockIdx.x * blockDim.x + threadIdx.x;
  if (i < n) {
    int p = atomicAdd(&cursor[rows[i]], 1);
    ev_s[p] = make_int2(cols[i], __float_as_int(vals[i]));
  }
}

// ---------------- dense GEMM: C[M,128] = A[M,K] @ W[K,128] ----------------
// m97-style 2-phase pipeline: BM=128, BN=128, BK=16, 256 threads, 8x8/thread.
// Double-buffered LDS staged entirely by global_load_lds (width 16) -> zero
// staging VGPRs. A row-major in LDS; 4-way read conflict fixed by
// pre-swizzling the per-lane GLOBAL source (q ^= (row>>2)&3 on f4-quads) and
// applying the same XOR on the LDS read (linear gload_lds dest, m173).
// No min-waves clamp: grid is ~3 blocks/CU anyway, let VGPRs float.

__device__ __forceinline__ void gload16(const float* src, float* dst_lds) {
  __builtin_amdgcn_global_load_lds(
      (const __attribute__((address_space(1))) void*)src,
      (__attribute__((address_space(3))) void*)dst_lds,
      16, 0, 0);
}

template<int K>
__global__ __launch_bounds__(256) void gemm_kernel(const float* __restrict__ A,
                                                   const float* __restrict__ W,
                                                   float* __restrict__ C, int M) {
  // float4-slot layouts: As slot = row*4 + (q ^ ((row>>2)&3)), q = k-quad 0..3
  //                      Bs slot = k*32 + colquad
  __shared__ __align__(16) float As[2][2048];   // 8 KB per buffer
  __shared__ __align__(16) float Bs[2][2048];   // 8 KB per buffer
  const int tid  = threadIdx.x;
  const int w    = tid >> 6;
  const int lane = tid & 63;
  const int r8   = tid >> 4;   // 0..15 -> rows r8*4+i (+64)
  const int c8   = tid & 15;   // 0..15 -> cols c8*4 (+64)
  const int block_row = blockIdx.x * 128;

  float acc[2][2][4][4] = {};   // [rh][ch][i][j]

  auto prefetch = [&](int t) {
    const int buf = t & 1;
    const int k0  = t * 16;
    #pragma unroll
    for (int j = 0; j < 2; ++j) {
      int s   = j * 256 + w * 64 + lane;      // A f4-slot this lane fills
      int row = s >> 2;
      int q   = (s & 3) ^ ((row >> 2) & 3);   // source pre-swizzle
      int grow = block_row + row;
      if (grow >= M) grow = M - 1;            // clamp: garbage lands in dead rows
      gload16(A + (size_t)grow * K + k0 + q * 4,
              &As[buf][(j * 256 + w * 64) * 4]);
    }
    #pragma unroll
    for (int j = 0; j < 2; ++j) {
      int s = j * 256 + w * 64 + lane;        // B f4-slot
      int r = s >> 5, cq = s & 31;
      gload16(W + (size_t)(k0 + r) * 128 + cq * 4,
              &Bs[buf][(j * 256 + w * 64) * 4]);
    }
  };

  constexpr int NT = K / 16;
  prefetch(0);
  for (int t = 0; t < NT; ++t) {
    __syncthreads();                 // drains tile-t loads (compiler vmcnt(0))
    if (t + 1 < NT) prefetch(t + 1); // in flight across compute(t)
    const float* as = As[t & 1];
    const float* bs = Bs[t & 1];
    #pragma unroll
    for (int q = 0; q < 4; ++q) {    // 4 k-quads = 16 kk
      // hold the A block (8 float4 = 32 regs), stream B in pairs (8 regs)
      float av[2][4][4];
      #pragma unroll
      for (int rh = 0; rh < 2; ++rh)
        #pragma unroll
        for (int i = 0; i < 4; ++i) {
          int row = rh * 64 + r8 * 4 + i;
          float4 a = *(const float4*)&as[(row * 4 + (q ^ ((row >> 2) & 3))) * 4];
          av[rh][i][0] = a.x; av[rh][i][1] = a.y;
          av[rh][i][2] = a.z; av[rh][i][3] = a.w;
        }
      #pragma unroll
      for (int j = 0; j < 4; ++j) {
        int kk = q * 4 + j;
        float4 b0 = *(const float4*)&bs[(kk * 32 + c8) * 4];
        float4 b1 = *(const float4*)&bs[(kk * 32 + 16 + c8) * 4];
        #pragma unroll
        for (int rh = 0; rh < 2; ++rh)
          #pragma unroll
          for (int i = 0; i < 4; ++i) {
            float a = av[rh][i][j];
            acc[rh][0][i][0] += a * b0.x; acc[rh][0][i][1] += a * b0.y;
            acc[rh][0][i][2] += a * b0.z; acc[rh][0][i][3] += a * b0.w;
            acc[rh][1][i][0] += a * b1.x; acc[rh][1][i][1] += a * b1.y;
            acc[rh][1][i][2] += a * b1.z; acc[rh][1][i][3] += a * b1.w;
          }
      }
    }
  }

  #pragma unroll
  for (int rh = 0; rh < 2; ++rh)
    #pragma unroll
    for (int i = 0; i < 4; ++i) {
      int grow = block_row + rh * 64 + r8 * 4 + i;
      if (grow < M) {
        #pragma unroll
        for (int ch = 0; ch < 2; ++ch) {
          float4 v = make_float4(acc[rh][ch][i][0], acc[rh][ch][i][1],
                                 acc[rh][ch][i][2], acc[rh][ch][i][3]);
          *(float4*)&C[(size_t)grow * 128 + ch * 64 + c8 * 4] = v;
        }
      }
    }
}

// ---------------- SpMM + bias + ReLU ----------------
// one 64-lane wave per output row; lane preloads one edge's packed (col,val);
// per-edge values via __shfl broadcast; unroll x8, dual acc chains -> 8
// outstanding 512B gathers per wave. (round-5 best config)

__global__ void spmm_kernel(const float* __restrict__ support, const int* __restrict__ row_ptr,
                            const int2* __restrict__ ev, const float* __restrict__ bias,
                            float* __restrict__ out, int n_nodes) {
  int row  = blockIdx.x * (blockDim.x >> 6) + (threadIdx.x >> 6);
  int lane = threadIdx.x & 63;
  if (row >= n_nodes) return;
  int beg = row_ptr[row], end = row_ptr[row + 1];
  float ax0 = 0.f, ay0 = 0.f, ax1 = 0.f, ay1 = 0.f;
  for (int chunk = beg; chunk < end; chunk += 64) {
    int idx = chunk + lane;
    int m = min(64, end - chunk);
    int2 ee = (idx < end) ? ev[idx] : make_int2(0, 0);
    int cl = ee.x;
    float vl = __int_as_float(ee.y);
    int e = 0;
    for (; e + 8 <= m; e += 8) {
      int   c0 = __shfl(cl, e + 0), c1 = __shfl(cl, e + 1);
      int   c2 = __shfl(cl, e + 2), c3 = __shfl(cl, e + 3);
      int   c4 = __shfl(cl, e + 4), c5 = __shfl(cl, e + 5);
      int   c6 = __shfl(cl, e + 6), c7 = __shfl(cl, e + 7);
      float v0 = __shfl(vl, e + 0), v1 = __shfl(vl, e + 1);
      float v2 = __shfl(vl, e + 2), v3 = __shfl(vl, e + 3);
      float v4 = __shfl(vl, e + 4), v5 = __shfl(vl, e + 5);
      float v6 = __shfl(vl, e + 6), v7 = __shfl(vl, e + 7);
      float2 s0 = *(const float2*)&support[(size_t)c0 * 128 + lane * 2];
      float2 s1 = *(const float2*)&support[(size_t)c1 * 128 + lane * 2];
      float2 s2 = *(const float2*)&support[(size_t)c2 * 128 + lane * 2];
      float2 s3 = *(const float2*)&support[(size_t)c3 * 128 + lane * 2];
      float2 s4 = *(const float2*)&support[(size_t)c4 * 128 + lane * 2];
      float2 s5 = *(const float2*)&support[(size_t)c5 * 128 + lane * 2];
      float2 s6 = *(const float2*)&support[(size_t)c6 * 128 + lane * 2];
      float2 s7 = *(const float2*)&support[(size_t)c7 * 128 + lane * 2];
      ax0 += v0 * s0.x; ay0 += v0 * s0.y;
      ax1 += v1 * s1.x; ay1 += v1 * s1.y;
      ax0 += v2 * s2.x; ay0 += v2 * s2.y;
      ax1 += v3 * s3.x; ay1 += v3 * s3.y;
      ax0 += v4 * s4.x; ay0 += v4 * s4.y;
      ax1 += v5 * s5.x; ay1 += v5 * s5.y;
      ax0 += v6 * s6.x; ay0 += v6 * s6.y;
      ax1 += v7 * s7.x; ay1 += v7 * s7.y;
    }
    for (; e < m; ++e) {
      int   ce = __shfl(cl, e);
      float ve = __shfl(vl, e);
      float2 s = *(const float2*)&support[(size_t)ce * 128 + lane * 2];
      ax0 += ve * s.x; ay0 += ve * s.y;
    }
  }
  float accx = ax0 + ax1, accy = ay0 + ay1;
  float2 b = *(const float2*)&bias[lane * 2];
  float2 o = make_float2(fmaxf(accx + b.x, 0.f), fmaxf(accy + b.y, 0.f));
  *(float2*)&out[(size_t)row * 128 + lane * 2] = o;
}

// ---------------- launch ----------------

extern "C" void kernel_launch(void* const* d_in, const int* in_sizes, int n_in,
                              void* d_out, int out_size, void* d_ws, size_t ws_size,
                              hipStream_t stream) {
  const float* x    = (const float*)d_in[0];
  const int*   erow = (const int*)d_in[1];
  const int*   ecol = (const int*)d_in[2];
  const float* evl  = (const float*)d_in[3];
  const float* W1   = (const float*)d_in[4];
  const float* b1   = (const float*)d_in[5];
  const float* W2   = (const float*)d_in[6];
  const float* b2   = (const float*)d_in[7];
  int n_nodes = in_sizes[0] / NFEAT;
  int n_edges = in_sizes[1];
  float* out = (float*)d_out;

  char* ws = (char*)d_ws;
  size_t off = 0;
  auto alloc = [&](size_t bytes) -> void* {
    void* p = ws + off;
    off += bytes;
    off = (off + 255) & ~(size_t)255;
    return p;
  };
  float* support = (float*)alloc((size_t)n_nodes * NHID * sizeof(float));
  int*   cnt     = (int*)alloc((size_t)n_nodes * sizeof(int));
  int*   row_ptr = (int*)alloc(((size_t)n_nodes + 1) * sizeof(int));
  int*   cursor  = (int*)alloc((size_t)n_nodes * sizeof(int));
  int2*  ev_s    = (int2*)alloc((size_t)n_edges * sizeof(int2));
  int nb = (n_nodes + SCAN_B - 1) / SCAN_B;
  int*   bsum    = (int*)alloc((size_t)(nb + 1) * sizeof(int));

  // CSR build (shared by all 5 layers)
  hipMemsetAsync(cnt, 0, (size_t)n_nodes * sizeof(int), stream);
  hist_kernel<<<(n_edges + 255) / 256, 256, 0, stream>>>(erow, cnt, n_edges);
  scan1_kernel<<<nb, 1024, 0, stream>>>(cnt, row_ptr, bsum, n_nodes);
  scan2_kernel<<<1, 64, 0, stream>>>(bsum, nb);
  scan3_kernel<<<(n_nodes + 255) / 256, 256, 0, stream>>>(row_ptr, bsum, cursor, n_nodes, nb);
  scatter_kernel<<<(n_edges + 255) / 256, 256, 0, stream>>>(erow, ecol, evl, cursor,
                                                            ev_s, n_edges);

  int gblocks = (n_nodes + 127) / 128;
  int sblocks = (n_nodes + 3) / 4;

  gemm_kernel<NFEAT><<<gblocks, 256, 0, stream>>>(x, W1, support, n_nodes);
  spmm_kernel<<<sblocks, 256, 0, stream>>>(support, row_ptr, ev_s, b1, out, n_nodes);

  for (int l = 0; l < 4; ++l) {
    gemm_kernel<NHID><<<gblocks, 256, 0, stream>>>(out, W2, support, n_nodes);
    spmm_kernel<<<sblocks, 256, 0, stream>>>(support, row_ptr, ev_s, b2, out, n_nodes);
  }
}

// Round 8
// 979.963 us; speedup vs baseline: 1.3471x; 1.0752x over previous
//
#include <hip/hip_runtime.h>

constexpr int NFEAT = 256;
constexpr int NHID  = 128;
constexpr int SCAN_B = 4096;   // elements per scan block (1024 threads x 4)

// ---------------- CSR build ----------------
// hist captures each edge's within-row rank from the atomicAdd return value;
// scatter then needs NO atomic: p = row_ptr[row] + rank (unique by const.)

__global__ void hist_kernel(const int* __restrict__ rows, int* __restrict__ cnt,
                            int* __restrict__ rank, int n) {
  int i = blockIdx.x * blockDim.x + threadIdx.x;
  if (i < n) rank[i] = atomicAdd(&cnt[rows[i]], 1);
}

__global__ void scan1_kernel(const int* __restrict__ cnt, int* __restrict__ part,
                             int* __restrict__ bsum, int n) {
  __shared__ int tmp[1024];
  int tid = threadIdx.x;
  int base = blockIdx.x * SCAN_B + tid * 4;
  int4 v = make_int4(0, 0, 0, 0);
  if (base + 4 <= n) {
    v = *(const int4*)&cnt[base];
  } else {
    if (base + 0 < n) v.x = cnt[base + 0];
    if (base + 1 < n) v.y = cnt[base + 1];
    if (base + 2 < n) v.z = cnt[base + 2];
    if (base + 3 < n) v.w = cnt[base + 3];
  }
  int s = v.x + v.y + v.z + v.w;
  tmp[tid] = s;
  __syncthreads();
  for (int off = 1; off < 1024; off <<= 1) {
    int t = (tid >= off) ? tmp[tid - off] : 0;
    __syncthreads();
    tmp[tid] += t;
    __syncthreads();
  }
  int excl = tmp[tid] - s;
  if (base + 0 < n) part[base + 0] = excl;
  if (base + 1 < n) part[base + 1] = excl + v.x;
  if (base + 2 < n) part[base + 2] = excl + v.x + v.y;
  if (base + 3 < n) part[base + 3] = excl + v.x + v.y + v.z;
  if (tid == 1023) bsum[blockIdx.x] = tmp[1023];
}

__global__ void scan2_kernel(int* __restrict__ bsum, int nb) {
  if (threadIdx.x == 0 && blockIdx.x == 0) {
    int run = 0;
    for (int i = 0; i < nb; ++i) { int t = bsum[i]; bsum[i] = run; run += t; }
    bsum[nb] = run;
  }
}

__global__ void scan3_kernel(int* __restrict__ row_ptr, const int* __restrict__ bsum,
                             int n, int nb) {
  int i = blockIdx.x * blockDim.x + threadIdx.x;
  if (i < n) row_ptr[i] += bsum[i / SCAN_B];
  if (i == 0) row_ptr[n] = bsum[nb];
}

// atomic-free scatter: coalesced reads (rows/cols/vals/rank), 4B L2-hot
// row_ptr gather, one independent random 8B write per edge.
__global__ void scatter_kernel(const int* __restrict__ rows, const int* __restrict__ cols,
                               const float* __restrict__ vals, const int* __restrict__ rank,
                               const int* __restrict__ row_ptr, int2* __restrict__ ev_s, int n) {
  int i = blockIdx.x * blockDim.x + threadIdx.x;
  if (i < n) {
    int p = row_ptr[rows[i]] + rank[i];
    ev_s[p] = make_int2(cols[i], __float_as_int(vals[i]));
  }
}

// ---------------- dense GEMM: C[M,128] = A[M,K] @ W[K,128] ----------------
// m97-style 2-phase pipeline: BM=128, BN=128, BK=16, 256 threads, 8x8/thread.
// Double-buffered LDS staged entirely by global_load_lds (width 16) -> zero
// staging VGPRs. A row-major in LDS; 4-way read conflict fixed by
// pre-swizzling the per-lane GLOBAL source (q ^= (row>>2)&3 on f4-quads) and
// applying the same XOR on the LDS read (linear gload_lds dest, m173).

__device__ __forceinline__ void gload16(const float* src, float* dst_lds) {
  __builtin_amdgcn_global_load_lds(
      (const __attribute__((address_space(1))) void*)src,
      (__attribute__((address_space(3))) void*)dst_lds,
      16, 0, 0);
}

template<int K>
__global__ __launch_bounds__(256) void gemm_kernel(const float* __restrict__ A,
                                                   const float* __restrict__ W,
                                                   float* __restrict__ C, int M) {
  __shared__ __align__(16) float As[2][2048];   // 8 KB per buffer
  __shared__ __align__(16) float Bs[2][2048];   // 8 KB per buffer
  const int tid  = threadIdx.x;
  const int w    = tid >> 6;
  const int lane = tid & 63;
  const int r8   = tid >> 4;   // 0..15 -> rows r8*4+i (+64)
  const int c8   = tid & 15;   // 0..15 -> cols c8*4 (+64)
  const int block_row = blockIdx.x * 128;

  float acc[2][2][4][4] = {};   // [rh][ch][i][j]

  auto prefetch = [&](int t) {
    const int buf = t & 1;
    const int k0  = t * 16;
    #pragma unroll
    for (int j = 0; j < 2; ++j) {
      int s   = j * 256 + w * 64 + lane;      // A f4-slot this lane fills
      int row = s >> 2;
      int q   = (s & 3) ^ ((row >> 2) & 3);   // source pre-swizzle
      int grow = block_row + row;
      if (grow >= M) grow = M - 1;            // clamp: garbage lands in dead rows
      gload16(A + (size_t)grow * K + k0 + q * 4,
              &As[buf][(j * 256 + w * 64) * 4]);
    }
    #pragma unroll
    for (int j = 0; j < 2; ++j) {
      int s = j * 256 + w * 64 + lane;        // B f4-slot
      int r = s >> 5, cq = s & 31;
      gload16(W + (size_t)(k0 + r) * 128 + cq * 4,
              &Bs[buf][(j * 256 + w * 64) * 4]);
    }
  };

  constexpr int NT = K / 16;
  prefetch(0);
  for (int t = 0; t < NT; ++t) {
    __syncthreads();                 // drains tile-t loads (compiler vmcnt(0))
    if (t + 1 < NT) prefetch(t + 1); // in flight across compute(t)
    const float* as = As[t & 1];
    const float* bs = Bs[t & 1];
    #pragma unroll
    for (int q = 0; q < 4; ++q) {    // 4 k-quads = 16 kk
      float av[2][4][4];
      #pragma unroll
      for (int rh = 0; rh < 2; ++rh)
        #pragma unroll
        for (int i = 0; i < 4; ++i) {
          int row = rh * 64 + r8 * 4 + i;
          float4 a = *(const float4*)&as[(row * 4 + (q ^ ((row >> 2) & 3))) * 4];
          av[rh][i][0] = a.x; av[rh][i][1] = a.y;
          av[rh][i][2] = a.z; av[rh][i][3] = a.w;
        }
      #pragma unroll
      for (int j = 0; j < 4; ++j) {
        int kk = q * 4 + j;
        float4 b0 = *(const float4*)&bs[(kk * 32 + c8) * 4];
        float4 b1 = *(const float4*)&bs[(kk * 32 + 16 + c8) * 4];
        #pragma unroll
        for (int rh = 0; rh < 2; ++rh)
          #pragma unroll
          for (int i = 0; i < 4; ++i) {
            float a = av[rh][i][j];
            acc[rh][0][i][0] += a * b0.x; acc[rh][0][i][1] += a * b0.y;
            acc[rh][0][i][2] += a * b0.z; acc[rh][0][i][3] += a * b0.w;
            acc[rh][1][i][0] += a * b1.x; acc[rh][1][i][1] += a * b1.y;
            acc[rh][1][i][2] += a * b1.z; acc[rh][1][i][3] += a * b1.w;
          }
      }
    }
  }

  #pragma unroll
  for (int rh = 0; rh < 2; ++rh)
    #pragma unroll
    for (int i = 0; i < 4; ++i) {
      int grow = block_row + rh * 64 + r8 * 4 + i;
      if (grow < M) {
        #pragma unroll
        for (int ch = 0; ch < 2; ++ch) {
          float4 v = make_float4(acc[rh][ch][i][0], acc[rh][ch][i][1],
                                 acc[rh][ch][i][2], acc[rh][ch][i][3]);
          *(float4*)&C[(size_t)grow * 128 + ch * 64 + c8 * 4] = v;
        }
      }
    }
}

// ---------------- SpMM + bias + ReLU ----------------
// TWO rows per 64-lane wave: lanes 0-31 -> row r0, lanes 32-63 -> row r1.
// Each lane gathers float4 (16B x 64 lanes = 2 edges per instruction).
// Per-half edge (col,val) preloaded 32-wide; broadcast via per-lane __shfl.
// Unroll x8 -> 16 edges (8 KB) in flight per wave.

__global__ void spmm_kernel(const float* __restrict__ support, const int* __restrict__ row_ptr,
                            const int2* __restrict__ ev, const float* __restrict__ bias,
                            float* __restrict__ out, int n_nodes) {
  int wid   = blockIdx.x * (blockDim.x >> 6) + (threadIdx.x >> 6);
  int lane  = threadIdx.x & 63;
  int half  = lane >> 5;
  int flane = lane & 31;
  int row   = wid * 2 + half;
  bool rv   = row < n_nodes;
  int beg = rv ? row_ptr[row]     : 0;
  int end = rv ? row_ptr[row + 1] : 0;
  int deg = end - beg;
  int mdeg = max(__shfl(deg, 0), __shfl(deg, 32));   // wave-uniform

  float4 acc = make_float4(0.f, 0.f, 0.f, 0.f);
  const int sb = half * 32;   // shfl base for my half

  for (int chunk = 0; chunk < mdeg; chunk += 32) {
    int idx = beg + chunk + flane;
    int2 ee = (idx < end) ? ev[idx] : make_int2(0, 0);
    int   cl = ee.x;
    float vl = __int_as_float(ee.y);
    int m = min(32, mdeg - chunk);
    int e = 0;
    for (; e + 8 <= m; e += 8) {
      int   c0 = __shfl(cl, sb + e + 0), c1 = __shfl(cl, sb + e + 1);
      int   c2 = __shfl(cl, sb + e + 2), c3 = __shfl(cl, sb + e + 3);
      int   c4 = __shfl(cl, sb + e + 4), c5 = __shfl(cl, sb + e + 5);
      int   c6 = __shfl(cl, sb + e + 6), c7 = __shfl(cl, sb + e + 7);
      float v0 = __shfl(vl, sb + e + 0), v1 = __shfl(vl, sb + e + 1);
      float v2 = __shfl(vl, sb + e + 2), v3 = __shfl(vl, sb + e + 3);
      float v4 = __shfl(vl, sb + e + 4), v5 = __shfl(vl, sb + e + 5);
      float v6 = __shfl(vl, sb + e + 6), v7 = __shfl(vl, sb + e + 7);
      float4 s0 = *(const float4*)&support[(size_t)c0 * 128 + flane * 4];
      float4 s1 = *(const float4*)&support[(size_t)c1 * 128 + flane * 4];
      float4 s2 = *(const float4*)&support[(size_t)c2 * 128 + flane * 4];
      float4 s3 = *(const float4*)&support[(size_t)c3 * 128 + flane * 4];
      float4 s4 = *(const float4*)&support[(size_t)c4 * 128 + flane * 4];
      float4 s5 = *(const float4*)&support[(size_t)c5 * 128 + flane * 4];
      float4 s6 = *(const float4*)&support[(size_t)c6 * 128 + flane * 4];
      float4 s7 = *(const float4*)&support[(size_t)c7 * 128 + flane * 4];
      acc.x += v0 * s0.x; acc.y += v0 * s0.y; acc.z += v0 * s0.z; acc.w += v0 * s0.w;
      acc.x += v1 * s1.x; acc.y += v1 * s1.y; acc.z += v1 * s1.z; acc.w += v1 * s1.w;
      acc.x += v2 * s2.x; acc.y += v2 * s2.y; acc.z += v2 * s2.z; acc.w += v2 * s2.w;
      acc.x += v3 * s3.x; acc.y += v3 * s3.y; acc.z += v3 * s3.z; acc.w += v3 * s3.w;
      acc.x += v4 * s4.x; acc.y += v4 * s4.y; acc.z += v4 * s4.z; acc.w += v4 * s4.w;
      acc.x += v5 * s5.x; acc.y += v5 * s5.y; acc.z += v5 * s5.z; acc.w += v5 * s5.w;
      acc.x += v6 * s6.x; acc.y += v6 * s6.y; acc.z += v6 * s6.z; acc.w += v6 * s6.w;
      acc.x += v7 * s7.x; acc.y += v7 * s7.y; acc.z += v7 * s7.z; acc.w += v7 * s7.w;
    }
    for (; e < m; ++e) {
      int   ce = __shfl(cl, sb + e);
      float ve = __shfl(vl, sb + e);
      float4 s = *(const float4*)&support[(size_t)ce * 128 + flane * 4];
      acc.x += ve * s.x; acc.y += ve * s.y; acc.z += ve * s.z; acc.w += ve * s.w;
    }
  }
  if (rv) {
    float4 b = *(const float4*)&bias[flane * 4];
    float4 o = make_float4(fmaxf(acc.x + b.x, 0.f), fmaxf(acc.y + b.y, 0.f),
                           fmaxf(acc.z + b.z, 0.f), fmaxf(acc.w + b.w, 0.f));
    *(float4*)&out[(size_t)row * 128 + flane * 4] = o;
  }
}

// ---------------- launch ----------------

extern "C" void kernel_launch(void* const* d_in, const int* in_sizes, int n_in,
                              void* d_out, int out_size, void* d_ws, size_t ws_size,
                              hipStream_t stream) {
  const float* x    = (const float*)d_in[0];
  const int*   erow = (const int*)d_in[1];
  const int*   ecol = (const int*)d_in[2];
  const float* evl  = (const float*)d_in[3];
  const float* W1   = (const float*)d_in[4];
  const float* b1   = (const float*)d_in[5];
  const float* W2   = (const float*)d_in[6];
  const float* b2   = (const float*)d_in[7];
  int n_nodes = in_sizes[0] / NFEAT;
  int n_edges = in_sizes[1];
  float* out = (float*)d_out;

  char* ws = (char*)d_ws;
  size_t off = 0;
  auto alloc = [&](size_t bytes) -> void* {
    void* p = ws + off;
    off += bytes;
    off = (off + 255) & ~(size_t)255;
    return p;
  };
  float* support = (float*)alloc((size_t)n_nodes * NHID * sizeof(float));
  int*   cnt     = (int*)alloc((size_t)n_nodes * sizeof(int));
  int*   row_ptr = (int*)alloc(((size_t)n_nodes + 1) * sizeof(int));
  int*   rank    = (int*)alloc((size_t)n_edges * sizeof(int));
  int2*  ev_s    = (int2*)alloc((size_t)n_edges * sizeof(int2));
  int nb = (n_nodes + SCAN_B - 1) / SCAN_B;
  int*   bsum    = (int*)alloc((size_t)(nb + 1) * sizeof(int));

  // CSR build (shared by all 5 layers)
  hipMemsetAsync(cnt, 0, (size_t)n_nodes * sizeof(int), stream);
  hist_kernel<<<(n_edges + 255) / 256, 256, 0, stream>>>(erow, cnt, rank, n_edges);
  scan1_kernel<<<nb, 1024, 0, stream>>>(cnt, row_ptr, bsum, n_nodes);
  scan2_kernel<<<1, 64, 0, stream>>>(bsum, nb);
  scan3_kernel<<<(n_nodes + 255) / 256, 256, 0, stream>>>(row_ptr, bsum, n_nodes, nb);
  scatter_kernel<<<(n_edges + 255) / 256, 256, 0, stream>>>(erow, ecol, evl, rank,
                                                            row_ptr, ev_s, n_edges);

  int gblocks = (n_nodes + 127) / 128;
  int sblocks = (n_nodes + 7) / 8;   // 4 waves/block x 2 rows/wave

  gemm_kernel<NFEAT><<<gblocks, 256, 0, stream>>>(x, W1, support, n_nodes);
  spmm_kernel<<<sblocks, 256, 0, stream>>>(support, row_ptr, ev_s, b1, out, n_nodes);

  for (int l = 0; l < 4; ++l) {
    gemm_kernel<NHID><<<gblocks, 256, 0, stream>>>(out, W2, support, n_nodes);
    spmm_kernel<<<sblocks, 256, 0, stream>>>(support, row_ptr, ev_s, b2, out, n_nodes);
  }
}